// Round 7
// baseline (808.152 us; speedup 1.0000x reference)
//
#include <hip/hip_runtime.h>

#define SEQ   512
#define NTHR  512
#define NBLK  256

typedef _Float16 f16x8 __attribute__((ext_vector_type(8)));
typedef float    f32x4 __attribute__((ext_vector_type(4)));

#define MFMA(a, b, c) __builtin_amdgcn_mfma_f32_16x16x32_f16((a), (b), (c), 0, 0, 0)

// sign-safe tanh via 2*sigmoid(2x)-1
__device__ __forceinline__ float tanh_(float x) {
    return fmaf(2.0f, __builtin_amdgcn_rcpf(1.0f + __builtin_amdgcn_exp2f(x * -2.8853900817779268f)), -1.0f);
}
#define SWZ(v, IMM) __int_as_float(__builtin_amdgcn_ds_swizzle(__float_as_int(v), IMM))

// Layer-pipelined schedule: wave w handles layer ell=w>>1 (om=w&1 selects 8 of
// 16 M-tiles). At tick tau, layer ell processes t = tau - ell; its inputs
// (h_{ell-1,t} and h_{ell,t-1}) were both written at tick tau-1 -> ONE barrier
// per tick. h buffers parity-flip per tick; zero-init makes warmup correct.
__global__ __launch_bounds__(NTHR, 1) void lstm4_pipe(
    const float* __restrict__ x,
    const float* __restrict__ W0, const float* __restrict__ B0,
    const float* __restrict__ W1, const float* __restrict__ B1,
    const float* __restrict__ W2, const float* __restrict__ B2,
    const float* __restrict__ W3, const float* __restrict__ B3,
    const float* __restrict__ ln_g, const float* __restrict__ ln_b,
    const float* __restrict__ Wout, const float* __restrict__ bout,
    float* __restrict__ out)
{
    __shared__ __align__(16) _Float16 hbuf[2][4][4][64];   // 4 KB  [parity][layer][b][k]
    __shared__ float xall[4][SEQ];                         // 8 KB
    __shared__ float part[16][2][4][4][3];                 // 6 KB LN partials (16 t-slots)
    __shared__ float sconst[2];

    const int tid  = threadIdx.x;
    const int lane = tid & 63;
    const int w    = tid >> 6;
    const int ell  = w >> 1;          // this wave's layer
    const int om   = w & 1;           // tile-half within layer
    const int lam  = lane >> 4;
    const int bc   = lane & 15;
    const int br   = bc & 3;
    const int bb   = blockIdx.x;

    // ---- stage x, zero h (both parities) ----
    for (int i = tid; i < 4 * SEQ; i += NTHR)
        xall[i >> 9][i & 511] = x[bb * 4 * SEQ + i];
    for (int i = tid; i < 2 * 4 * 4 * 64; i += NTHR)
        ((_Float16*)hbuf)[i] = (_Float16)0.0f;

    if (tid < 64) {
        float a = ln_g[tid] * Wout[tid];
        float b = ln_b[tid] * Wout[tid];
#pragma unroll
        for (int off = 32; off > 0; off >>= 1) {
            a += __shfl_xor(a, off, 64);
            b += __shfl_xor(b, off, 64);
        }
        if (tid == 0) { sconst[0] = a; sconst[1] = b; }
    }

    const float* Wp = (ell == 0) ? W0 : (ell == 1) ? W1 : (ell == 2) ? W2 : W3;
    const float* Bp = (ell == 0) ? B0 : (ell == 1) ? B1 : (ell == 2) ? B2 : B3;

    // ---- per-wave weights: 8 tiles of this layer, gate-permuted cols ----
    // tile T: m = T*4+lam, gate = r; A-row rho=bc -> col (rho&3)*64 + T*4 + (rho>>2)
    f16x8 wf[8][4];
    f32x4 biasv[8];
    float gw[8];
    int   wr[8];
#pragma unroll
    for (int i = 0; i < 8; ++i) {
        const int T  = om * 8 + i;
        const int cA = (bc & 3) * 64 + T * 4 + (bc >> 2);
        if (ell == 0) {
#pragma unroll
            for (int kt = 0; kt < 2; ++kt)
#pragma unroll
                for (int e = 0; e < 8; ++e)
                    wf[i][kt][e] = (_Float16)W0[(1 + kt * 32 + lam * 8 + e) * 256 + cA];
#pragma unroll
            for (int e = 0; e < 8; ++e) { wf[i][2][e] = (_Float16)0.0f; wf[i][3][e] = (_Float16)0.0f; }
            if (lam == 0) wf[i][2][0] = (_Float16)W0[cA];   // x weight, one-hot A-frag
        } else {
#pragma unroll
            for (int kt = 0; kt < 4; ++kt)        // kt 0..1 = in-h rows, 2..3 = self-h rows
#pragma unroll
                for (int e = 0; e < 8; ++e)
                    wf[i][kt][e] = (_Float16)Wp[(kt * 32 + lam * 8 + e) * 256 + cA];
        }
        const int m = T * 4 + lam;
#pragma unroll
        for (int r = 0; r < 4; ++r) biasv[i][r] = Bp[r * 64 + m];
        gw[i] = ln_g[m] * Wout[m];
        wr[i] = bc * 128 + (((m >> 3) ^ bc) * 16) + (m & 7) * 2;
    }

    // LDS B-frag read offsets (16B-chunk XOR swizzle), pad lanes broadcast br
    const int a0 = br * 128 + ((lam)     ^ br) * 16;
    const int a1 = br * 128 + ((4 + lam) ^ br) * 16;
    const bool gl = (bc < 4);

    // distributed-gate lane constants
    const bool k1b = (bc & 4) != 0;
    const bool k2b = (bc & 8) != 0;
    const bool isg = ((bc >> 2) == 2);
    const float ga = isg ? 2.0f : 1.0f;
    const float gb = isg ? -2.8853900817779268f : -1.4426950408889634f;
    const float gc = isg ? -1.0f : 0.0f;

    float cst[8] = {0.f,0.f,0.f,0.f,0.f,0.f,0.f,0.f};
    char* const hb = (char*)hbuf;

    __syncthreads();
    const float Sgw = sconst[0];
    const float Sbw = sconst[1] + bout[0];

    for (int tau = 0; tau < SEQ + 3; ++tau) {
        const char* bR = hb + (((tau + 1) & 1) ? 2048 : 0);   // written last tick
        char*       bW = hb + (((tau    ) & 1) ? 2048 : 0);   // written this tick
        const int  t      = tau - ell;
        const bool active = (t >= 0) && (t < SEQ);

        if (active) {
            f16x8 b0, b1, b2, b3;
            if (ell == 0) {
                b0 = *(const f16x8*)(bR + a0);         // self-h (layer 0 buffer)
                b1 = *(const f16x8*)(bR + a1);
                f16x8 xf;
#pragma unroll
                for (int e = 0; e < 8; ++e) xf[e] = (_Float16)0.0f;
                if (lam == 0) xf[0] = (_Float16)xall[br][t];   // one-hot x B-frag
                b2 = xf; b3 = xf;                      // wf[i][3]==0 -> no contribution
            } else {
                const char* bIn   = bR + (ell - 1) * 512;
                const char* bSelf = bR + ell * 512;
                b0 = *(const f16x8*)(bIn + a0);
                b1 = *(const f16x8*)(bIn + a1);
                b2 = *(const f16x8*)(bSelf + a0);
                b3 = *(const f16x8*)(bSelf + a1);
            }

            float s1 = 0.0f, s2 = 0.0f, s3 = 0.0f;
            char* hw = bW + ell * 512;
#pragma unroll
            for (int i = 0; i < 8; ++i) {
                f32x4 acc = MFMA(wf[i][0], b0, biasv[i]);
                acc = MFMA(wf[i][1], b1, acc);
                acc = MFMA(wf[i][2], b2, acc);
                acc = MFMA(wf[i][3], b3, acc);
                // distributed gates over the bc quad (lane k=bc>>2 does gate k)
                float xs = k1b ? acc[1] : acc[0];
                float xu = k1b ? acc[3] : acc[2];
                xs = k2b ? xu : xs;
                const float y  = fmaf(ga, __builtin_amdgcn_rcpf(1.0f + __builtin_amdgcn_exp2f(gb * xs)), gc);
                const float yf = SWZ(y, 0x101F);   // xor 4
                const float yg = SWZ(y, 0x201F);   // xor 8
                const float yo = SWZ(y, 0x301F);   // xor 12
                cst[i] = fmaf(yf, cst[i], y * yg); // real on k==0 lanes
                const float hn = yo * tanh_(cst[i]);
                if (gl) *(_Float16*)(hw + wr[i]) = (_Float16)hn;
                if (ell == 3) { s1 += hn; s2 = fmaf(hn, hn, s2); s3 = fmaf(hn, gw[i], s3); }
            }
            if (ell == 3 && gl) {
                float* pp = &part[t & 15][om][lam][br][0];
                pp[0] = s1; pp[1] = s2; pp[2] = s3;
            }
        }
        __syncthreads();

        // ---- LN + projection for 8 finished timesteps (all waves) ----
        const int t3 = tau - 3;
        if (t3 >= 7 && (t3 & 7) == 7) {
            const int row = tid >> 4, sub = tid & 15;
            const int sl  = row >> 2, b = row & 3;
            const int idx = sub & 7, o2 = idx >> 2, l2 = idx & 3;
            const int slot = (t3 - 7 + sl) & 15;
            float u1 = part[slot][o2][l2][b][0];
            float u2 = part[slot][o2][l2][b][1];
            float u3 = part[slot][o2][l2][b][2];
#pragma unroll
            for (int off = 1; off <= 4; off <<= 1) {
                u1 += __shfl_xor(u1, off, 64);
                u2 += __shfl_xor(u2, off, 64);
                u3 += __shfl_xor(u3, off, 64);
            }
            if (sub == 0) {
                const float mu = u1 * (1.0f / 64.0f);
                float var = fmaf(u2, 1.0f / 64.0f, -mu * mu);
                var = fmaxf(var, 0.0f);
                const float rs = rsqrtf(var + 1e-5f);
                out[(bb * 4 + b) * SEQ + (t3 - 7) + sl] = fmaf(rs, fmaf(-mu, Sgw, u3), Sbw);
            }
        }
    }
}

extern "C" void kernel_launch(void* const* d_in, const int* in_sizes, int n_in,
                              void* d_out, int out_size, void* d_ws, size_t ws_size,
                              hipStream_t stream)
{
    const float* x    = (const float*)d_in[0];
    const float* W0   = (const float*)d_in[1];
    const float* B0   = (const float*)d_in[2];
    const float* W1   = (const float*)d_in[3];
    const float* B1   = (const float*)d_in[4];
    const float* W2   = (const float*)d_in[5];
    const float* B2   = (const float*)d_in[6];
    const float* W3   = (const float*)d_in[7];
    const float* B3   = (const float*)d_in[8];
    const float* ln_g = (const float*)d_in[9];
    const float* ln_b = (const float*)d_in[10];
    const float* Wout = (const float*)d_in[11];
    const float* bout = (const float*)d_in[12];
    float* out = (float*)d_out;

    lstm4_pipe<<<NBLK, NTHR, 0, stream>>>(x, W0, B0, W1, B1, W2, B2, W3, B3,
                                          ln_g, ln_b, Wout, bout, out);
}

// Round 9
// 713.785 us; speedup vs baseline: 1.1322x; 1.1322x over previous
//
#include <hip/hip_runtime.h>

#define SEQ   512
#define NTHR  1024
#define NBLK  256

typedef _Float16 f16x8 __attribute__((ext_vector_type(8)));
typedef float    f32x4 __attribute__((ext_vector_type(4)));

#define MFMA(a, b, c) __builtin_amdgcn_mfma_f32_16x16x32_f16((a), (b), (c), 0, 0, 0)

// sign-safe tanh via 2*sigmoid(2x)-1
__device__ __forceinline__ float tanh_(float x) {
    return fmaf(2.0f, __builtin_amdgcn_rcpf(1.0f + __builtin_amdgcn_exp2f(x * -2.8853900817779268f)), -1.0f);
}
#define SWZ(v, IMM) __int_as_float(__builtin_amdgcn_ds_swizzle(__float_as_int(v), IMM))

// Layer-pipelined, 16 waves: wave w -> layer ell=w>>2, quarter om=w&3 (4 M-tiles).
// At tick tau, layer ell processes t = tau - ell; inputs h_{ell-1,t} and
// h_{ell,t-1} were written last tick -> ONE barrier per tick. 4 waves/SIMD.
__global__ __launch_bounds__(NTHR, 4) void lstm4_pipe16(
    const float* __restrict__ x,
    const float* __restrict__ W0, const float* __restrict__ B0,
    const float* __restrict__ W1, const float* __restrict__ B1,
    const float* __restrict__ W2, const float* __restrict__ B2,
    const float* __restrict__ W3, const float* __restrict__ B3,
    const float* __restrict__ ln_g, const float* __restrict__ ln_b,
    const float* __restrict__ Wout, const float* __restrict__ bout,
    float* __restrict__ out)
{
    __shared__ __align__(16) _Float16 hbuf[2][4][4][64];   // 4 KB  [parity][layer][b][k]
    __shared__ float xall[4][SEQ];                         // 8 KB
    __shared__ float part[16][4][4][4][3];                 // 12 KB LN partials
    __shared__ __align__(16) float blds[4][16][4][4];      // 4 KB biases [ell][T][lam][r]
    __shared__ float sconst[2];

    const int tid  = threadIdx.x;
    const int lane = tid & 63;
    const int w    = tid >> 6;        // wave 0..15
    const int ell  = w >> 2;          // layer
    const int om   = w & 3;           // tile quarter
    const int lam  = lane >> 4;
    const int bc   = lane & 15;
    const int br   = bc & 3;
    const int bb   = blockIdx.x;

    // ---- stage x, zero h (both parities) ----
    for (int i = tid; i < 4 * SEQ; i += NTHR)
        xall[i >> 9][i & 511] = x[bb * 4 * SEQ + i];
    for (int i = tid; i < 2 * 4 * 4 * 64; i += NTHR)
        ((_Float16*)hbuf)[i] = (_Float16)0.0f;

    // biases -> LDS: [ell][T][lam][r], linear index == tid
    {
        const int L = tid >> 8, idx = tid & 255;
        const int T = idx >> 4, lm = (idx >> 2) & 3, r = idx & 3;
        const float* Bp = (L == 0) ? B0 : (L == 1) ? B1 : (L == 2) ? B2 : B3;
        ((float*)blds)[tid] = Bp[r * 64 + T * 4 + lm];
    }

    if (tid < 64) {
        float a = ln_g[tid] * Wout[tid];
        float b = ln_b[tid] * Wout[tid];
#pragma unroll
        for (int off = 32; off > 0; off >>= 1) {
            a += __shfl_xor(a, off, 64);
            b += __shfl_xor(b, off, 64);
        }
        if (tid == 0) { sconst[0] = a; sconst[1] = b; }
    }

    const float* Wp = (ell == 0) ? W0 : (ell == 1) ? W1 : (ell == 2) ? W2 : W3;

    // ---- per-wave weights: 4 tiles, gate-permuted cols ----
    f16x8 wf[4][4];
    float gw[4];
    int   wr[4];
#pragma unroll
    for (int i = 0; i < 4; ++i) {
        const int T  = om * 4 + i;
        const int cA = (bc & 3) * 64 + T * 4 + (bc >> 2);
        if (ell == 0) {
#pragma unroll
            for (int kt = 0; kt < 2; ++kt)
#pragma unroll
                for (int e = 0; e < 8; ++e)
                    wf[i][kt][e] = (_Float16)W0[(1 + kt * 32 + lam * 8 + e) * 256 + cA];
#pragma unroll
            for (int e = 0; e < 8; ++e) { wf[i][2][e] = (_Float16)0.0f; wf[i][3][e] = (_Float16)0.0f; }
            if (lam == 0) wf[i][2][0] = (_Float16)W0[cA];   // x weight, one-hot A-frag
        } else {
#pragma unroll
            for (int kt = 0; kt < 4; ++kt)        // kt 0..1 = in-h, 2..3 = self-h
#pragma unroll
                for (int e = 0; e < 8; ++e)
                    wf[i][kt][e] = (_Float16)Wp[(kt * 32 + lam * 8 + e) * 256 + cA];
        }
        const int m = T * 4 + lam;
        gw[i] = ln_g[m] * Wout[m];
        wr[i] = bc * 128 + (((m >> 3) ^ bc) * 16) + (m & 7) * 2;
    }

    // LDS B-frag read offsets (16B-chunk XOR swizzle), pad lanes broadcast br
    const int a0 = br * 128 + ((lam)     ^ br) * 16;
    const int a1 = br * 128 + ((4 + lam) ^ br) * 16;
    const bool gl = (bc < 4);

    // distributed-gate lane constants (lane k=bc>>2 evaluates gate k)
    const bool k1b = (bc & 4) != 0;
    const bool k2b = (bc & 8) != 0;
    const bool isg = ((bc >> 2) == 2);
    const float ga = isg ? 2.0f : 1.0f;
    const float gb = isg ? -2.8853900817779268f : -1.4426950408889634f;
    const float gc = isg ? -1.0f : 0.0f;

    float cst[4] = {0.f, 0.f, 0.f, 0.f};
    char* const hb = (char*)hbuf;
    const char* const bldsW = (const char*)blds + (ell * 16 + om * 4) * 64 + lam * 16;

    __syncthreads();
    const float Sgw = sconst[0];
    const float Sbw = sconst[1] + bout[0];

    for (int tau = 0; tau < SEQ + 3; ++tau) {
        const char* bR = hb + (((tau + 1) & 1) ? 2048 : 0);   // written last tick
        char*       bW = hb + (((tau    ) & 1) ? 2048 : 0);   // written this tick
        const int  t      = tau - ell;
        const bool active = (t >= 0) && (t < SEQ);

        if (active) {
            f16x8 b0, b1, b2, b3;
            if (ell == 0) {
                b0 = *(const f16x8*)(bR + a0);         // self-h (layer 0 buffer)
                b1 = *(const f16x8*)(bR + a1);
                f16x8 xf;
#pragma unroll
                for (int e = 0; e < 8; ++e) xf[e] = (_Float16)0.0f;
                if (lam == 0) xf[0] = (_Float16)xall[br][t];   // one-hot x B-frag
                b2 = xf; b3 = xf;                      // wf[i][3]==0 -> no contribution
            } else {
                const char* bIn   = bR + (ell - 1) * 512;
                const char* bSelf = bR + ell * 512;
                b0 = *(const f16x8*)(bIn + a0);
                b1 = *(const f16x8*)(bIn + a1);
                b2 = *(const f16x8*)(bSelf + a0);
                b3 = *(const f16x8*)(bSelf + a1);
            }

            float s1 = 0.0f, s2 = 0.0f, s3 = 0.0f;
            char* hw = bW + ell * 512;
#pragma unroll
            for (int i = 0; i < 4; ++i) {
                f32x4 acc = *(const f32x4*)(bldsW + i * 64);
                acc = MFMA(wf[i][0], b0, acc);
                acc = MFMA(wf[i][1], b1, acc);
                acc = MFMA(wf[i][2], b2, acc);
                acc = MFMA(wf[i][3], b3, acc);
                // distributed gates over the bc quad
                float xs = k1b ? acc[1] : acc[0];
                float xu = k1b ? acc[3] : acc[2];
                xs = k2b ? xu : xs;
                const float y  = fmaf(ga, __builtin_amdgcn_rcpf(1.0f + __builtin_amdgcn_exp2f(gb * xs)), gc);
                const float yf = SWZ(y, 0x101F);   // xor 4
                const float yg = SWZ(y, 0x201F);   // xor 8
                const float yo = SWZ(y, 0x301F);   // xor 12
                cst[i] = fmaf(yf, cst[i], y * yg); // real on k==0 lanes
                const float hn = yo * tanh_(cst[i]);
                if (gl) *(_Float16*)(hw + wr[i]) = (_Float16)hn;
                if (ell == 3) { s1 += hn; s2 = fmaf(hn, hn, s2); s3 = fmaf(hn, gw[i], s3); }
            }
            if (ell == 3 && gl) {
                float* pp = &part[t & 15][om][lam][br][0];
                pp[0] = s1; pp[1] = s2; pp[2] = s3;
            }
        }
        __syncthreads();

        // ---- LN + projection for 8 finished timesteps ----
        const int t3 = tau - 3;
        if (t3 >= 7 && (t3 & 7) == 7) {
            const int row = tid >> 4, sub = tid & 15;
            if (row < 32) {
                const int sl = row >> 2, b = row & 3;
                const int slot = (t3 - 7 + sl) & 15;
                float u1 = part[slot][sub >> 2][sub & 3][b][0];
                float u2 = part[slot][sub >> 2][sub & 3][b][1];
                float u3 = part[slot][sub >> 2][sub & 3][b][2];
#pragma unroll
                for (int off = 1; off <= 8; off <<= 1) {
                    u1 += __shfl_xor(u1, off, 64);
                    u2 += __shfl_xor(u2, off, 64);
                    u3 += __shfl_xor(u3, off, 64);
                }
                if (sub == 0) {
                    const float mu = u1 * (1.0f / 64.0f);
                    float var = fmaf(u2, 1.0f / 64.0f, -mu * mu);
                    var = fmaxf(var, 0.0f);
                    const float rs = rsqrtf(var + 1e-5f);
                    out[(bb * 4 + b) * SEQ + (t3 - 7) + sl] = fmaf(rs, fmaf(-mu, Sgw, u3), Sbw);
                }
            }
        }
    }
}

extern "C" void kernel_launch(void* const* d_in, const int* in_sizes, int n_in,
                              void* d_out, int out_size, void* d_ws, size_t ws_size,
                              hipStream_t stream)
{
    const float* x    = (const float*)d_in[0];
    const float* W0   = (const float*)d_in[1];
    const float* B0   = (const float*)d_in[2];
    const float* W1   = (const float*)d_in[3];
    const float* B1   = (const float*)d_in[4];
    const float* W2   = (const float*)d_in[5];
    const float* B2   = (const float*)d_in[6];
    const float* W3   = (const float*)d_in[7];
    const float* B3   = (const float*)d_in[8];
    const float* ln_g = (const float*)d_in[9];
    const float* ln_b = (const float*)d_in[10];
    const float* Wout = (const float*)d_in[11];
    const float* bout = (const float*)d_in[12];
    float* out = (float*)d_out;

    lstm4_pipe16<<<NBLK, NTHR, 0, stream>>>(x, W0, B0, W1, B1, W2, B2, W3, B3,
                                            ln_g, ln_b, Wout, bout, out);
}

// Round 10
// 560.643 us; speedup vs baseline: 1.4415x; 1.2732x over previous
//
#include <hip/hip_runtime.h>

#define SEQ   512
#define NTHR  1024
#define NBLK  256

typedef _Float16 f16x8 __attribute__((ext_vector_type(8)));
typedef float    f32x4 __attribute__((ext_vector_type(4)));

#define MFMA(a, b, c) __builtin_amdgcn_mfma_f32_16x16x32_f16((a), (b), (c), 0, 0, 0)

__device__ __forceinline__ float sig_(float x) {
    return __builtin_amdgcn_rcpf(1.0f + __builtin_amdgcn_exp2f(x * -1.4426950408889634f));
}
// sign-safe tanh via 2*sigmoid(2x)-1
__device__ __forceinline__ float tanh_(float x) {
    return fmaf(2.0f, __builtin_amdgcn_rcpf(1.0f + __builtin_amdgcn_exp2f(x * -2.8853900817779268f)), -1.0f);
}

// Layer-pipelined, 16 waves: wave w -> layer ell=w>>2, quarter om=w&3 (4 M-tiles).
// Tick tau: layer ell processes t = tau - ell. ONE barrier per tick.
// Gate-post: replica-quad member k=bc>>2 owns tile k fully IN-LANE (acc[0..3] of
// tile k are gates i,f,g,o of (m=(om*4+k)*4+lam, b=bc&3)); no cross-lane swizzles.
__global__ __launch_bounds__(NTHR, 4) void lstm4_pipe16b(
    const float* __restrict__ x,
    const float* __restrict__ W0, const float* __restrict__ B0,
    const float* __restrict__ W1, const float* __restrict__ B1,
    const float* __restrict__ W2, const float* __restrict__ B2,
    const float* __restrict__ W3, const float* __restrict__ B3,
    const float* __restrict__ ln_g, const float* __restrict__ ln_b,
    const float* __restrict__ Wout, const float* __restrict__ bout,
    float* __restrict__ out)
{
    __shared__ __align__(16) _Float16 hbuf[2][4][4][64];   // 4 KB  [parity][layer][b][k]
    __shared__ float xall[4][SEQ];                         // 8 KB
    __shared__ float part[16][4][4][3];                    // 3 KB LN partials [slot][om][b][c]
    __shared__ float sconst[2];

    const int tid  = threadIdx.x;
    const int lane = tid & 63;
    const int w    = tid >> 6;        // wave 0..15
    const int ell  = w >> 2;          // layer
    const int om   = w & 3;           // tile quarter
    const int lam  = lane >> 4;
    const int bc   = lane & 15;
    const int br   = bc & 3;
    const int k    = bc >> 2;         // quad member -> owned tile
    const int bb   = blockIdx.x;

    // ---- stage x, zero h (both parities) ----
    for (int i = tid; i < 4 * SEQ; i += NTHR)
        xall[i >> 9][i & 511] = x[bb * 4 * SEQ + i];
    for (int i = tid; i < 2 * 4 * 4 * 64; i += NTHR)
        ((_Float16*)hbuf)[i] = (_Float16)0.0f;

    if (tid < 64) {
        float a = ln_g[tid] * Wout[tid];
        float b = ln_b[tid] * Wout[tid];
#pragma unroll
        for (int off = 32; off > 0; off >>= 1) {
            a += __shfl_xor(a, off, 64);
            b += __shfl_xor(b, off, 64);
        }
        if (tid == 0) { sconst[0] = a; sconst[1] = b; }
    }

    const float* Wp = (ell == 0) ? W0 : (ell == 1) ? W1 : (ell == 2) ? W2 : W3;
    const float* Bp = (ell == 0) ? B0 : (ell == 1) ? B1 : (ell == 2) ? B2 : B3;

    // ---- per-wave weights: 4 tiles, gate-permuted cols; biases in VGPR ----
    f16x8 wf[4][4];
    f32x4 biasv[4];
#pragma unroll
    for (int i = 0; i < 4; ++i) {
        const int T  = om * 4 + i;
        const int cA = (bc & 3) * 64 + T * 4 + (bc >> 2);
        if (ell == 0) {
#pragma unroll
            for (int kt = 0; kt < 2; ++kt)
#pragma unroll
                for (int e = 0; e < 8; ++e)
                    wf[i][kt][e] = (_Float16)W0[(1 + kt * 32 + lam * 8 + e) * 256 + cA];
#pragma unroll
            for (int e = 0; e < 8; ++e) { wf[i][2][e] = (_Float16)0.0f; wf[i][3][e] = (_Float16)0.0f; }
            if (lam == 0) wf[i][2][0] = (_Float16)W0[cA];   // x weight, one-hot A-frag
        } else {
#pragma unroll
            for (int kt = 0; kt < 4; ++kt)        // kt 0..1 = in-h, 2..3 = self-h
#pragma unroll
                for (int e = 0; e < 8; ++e)
                    wf[i][kt][e] = (_Float16)Wp[(kt * 32 + lam * 8 + e) * 256 + cA];
        }
#pragma unroll
        for (int r = 0; r < 4; ++r)
            biasv[i][r] = Bp[r * 64 + T * 4 + lam];
    }

    // owned-tile constants
    const int   mK  = (om * 4 + k) * 4 + lam;
    const float gwK = ln_g[mK] * Wout[mK];
    const int   wrK = br * 128 + (((mK >> 3) ^ br) * 16) + (mK & 7) * 2;

    // LDS B-frag read offsets (16B-chunk XOR swizzle), pad lanes broadcast br
    const int a0 = br * 128 + ((lam)     ^ br) * 16;
    const int a1 = br * 128 + ((4 + lam) ^ br) * 16;

    const bool k1b = (bc & 4) != 0;
    const bool k2b = (bc & 8) != 0;

    float cstK = 0.0f;
    char* const hb = (char*)hbuf;

    __syncthreads();
    const float Sgw = sconst[0];
    const float Sbw = sconst[1] + bout[0];

    for (int tau = 0; tau < SEQ + 3; ++tau) {
        const char* bR = hb + (((tau + 1) & 1) ? 2048 : 0);   // written last tick
        char*       bW = hb + (((tau    ) & 1) ? 2048 : 0);   // written this tick
        const int  t      = tau - ell;
        const bool active = (t >= 0) && (t < SEQ);

        if (active) {
            f16x8 b0, b1, b2, b3;
            if (ell == 0) {
                b0 = *(const f16x8*)(bR + a0);         // self-h (layer 0 buffer)
                b1 = *(const f16x8*)(bR + a1);
                f16x8 xf;
#pragma unroll
                for (int e = 0; e < 8; ++e) xf[e] = (_Float16)0.0f;
                if (lam == 0) xf[0] = (_Float16)xall[br][t];   // one-hot x B-frag
                b2 = xf; b3 = xf;
            } else {
                const char* bIn   = bR + (ell - 1) * 512;
                const char* bSelf = bR + ell * 512;
                b0 = *(const f16x8*)(bIn + a0);
                b1 = *(const f16x8*)(bIn + a1);
                b2 = *(const f16x8*)(bSelf + a0);
                b3 = *(const f16x8*)(bSelf + a1);
            }

            f32x4 A0 = MFMA(wf[0][0], b0, biasv[0]);
            f32x4 A1 = MFMA(wf[1][0], b0, biasv[1]);
            f32x4 A2 = MFMA(wf[2][0], b0, biasv[2]);
            f32x4 A3 = MFMA(wf[3][0], b0, biasv[3]);
            A0 = MFMA(wf[0][1], b1, A0);  A1 = MFMA(wf[1][1], b1, A1);
            A2 = MFMA(wf[2][1], b1, A2);  A3 = MFMA(wf[3][1], b1, A3);
            A0 = MFMA(wf[0][2], b2, A0);  A1 = MFMA(wf[1][2], b2, A1);
            A2 = MFMA(wf[2][2], b2, A2);  A3 = MFMA(wf[3][2], b2, A3);
            A0 = MFMA(wf[0][3], b3, A0);  A1 = MFMA(wf[1][3], b3, A1);
            A2 = MFMA(wf[2][3], b3, A2);  A3 = MFMA(wf[3][3], b3, A3);

            // select owned tile k's acc (cndmask ladder, no array indexing)
            const f32x4 s01 = k1b ? A1 : A0;
            const f32x4 s23 = k1b ? A3 : A2;
            const f32x4 aK  = k2b ? s23 : s01;

            // straight-line in-lane gates
            const float gi = sig_(aK[0]);
            const float gf = sig_(aK[1]);
            const float gg = tanh_(aK[2]);
            const float go = sig_(aK[3]);
            cstK = fmaf(gf, cstK, gi * gg);
            const float hn = go * tanh_(cstK);
            *(_Float16*)(bW + ell * 512 + wrK) = (_Float16)hn;   // all 64 lanes, 1 write each

            if (ell == 3) {
                float v1 = hn, v2 = hn * hn, v3 = hn * gwK;
                v1 += __shfl_xor(v1, 4, 64);  v2 += __shfl_xor(v2, 4, 64);  v3 += __shfl_xor(v3, 4, 64);
                v1 += __shfl_xor(v1, 8, 64);  v2 += __shfl_xor(v2, 8, 64);  v3 += __shfl_xor(v3, 8, 64);
                v1 += __shfl_xor(v1, 16, 64); v2 += __shfl_xor(v2, 16, 64); v3 += __shfl_xor(v3, 16, 64);
                v1 += __shfl_xor(v1, 32, 64); v2 += __shfl_xor(v2, 32, 64); v3 += __shfl_xor(v3, 32, 64);
                if (bc < 4) {
                    float* pp = &part[t & 15][om][bc][0];
                    pp[0] = v1; pp[1] = v2; pp[2] = v3;
                }
            }
        }
        __syncthreads();

        // ---- LN + projection for 8 finished timesteps ----
        const int t3 = tau - 3;
        if (t3 >= 7 && (t3 & 7) == 7) {
            const int row = tid >> 4, sub = tid & 15;
            if (row < 32) {
                const int sl = row >> 2, b = row & 3;
                const int slot = (t3 - 7 + sl) & 15;
                float u1 = part[slot][sub & 3][b][0];
                float u2 = part[slot][sub & 3][b][1];
                float u3 = part[slot][sub & 3][b][2];
                u1 += __shfl_xor(u1, 1, 64); u2 += __shfl_xor(u2, 1, 64); u3 += __shfl_xor(u3, 1, 64);
                u1 += __shfl_xor(u1, 2, 64); u2 += __shfl_xor(u2, 2, 64); u3 += __shfl_xor(u3, 2, 64);
                if (sub == 0) {
                    const float mu = u1 * (1.0f / 64.0f);
                    float var = fmaf(u2, 1.0f / 64.0f, -mu * mu);
                    var = fmaxf(var, 0.0f);
                    const float rs = rsqrtf(var + 1e-5f);
                    out[(bb * 4 + b) * SEQ + (t3 - 7) + sl] = fmaf(rs, fmaf(-mu, Sgw, u3), Sbw);
                }
            }
        }
    }
}

extern "C" void kernel_launch(void* const* d_in, const int* in_sizes, int n_in,
                              void* d_out, int out_size, void* d_ws, size_t ws_size,
                              hipStream_t stream)
{
    const float* x    = (const float*)d_in[0];
    const float* W0   = (const float*)d_in[1];
    const float* B0   = (const float*)d_in[2];
    const float* W1   = (const float*)d_in[3];
    const float* B1   = (const float*)d_in[4];
    const float* W2   = (const float*)d_in[5];
    const float* B2   = (const float*)d_in[6];
    const float* W3   = (const float*)d_in[7];
    const float* B3   = (const float*)d_in[8];
    const float* ln_g = (const float*)d_in[9];
    const float* ln_b = (const float*)d_in[10];
    const float* Wout = (const float*)d_in[11];
    const float* bout = (const float*)d_in[12];
    float* out = (float*)d_out;

    lstm4_pipe16b<<<NBLK, NTHR, 0, stream>>>(x, W0, B0, W1, B1, W2, B2, W3, B3,
                                             ln_g, ln_b, Wout, bout, out);
}